// Round 21
// baseline (74.791 us; speedup 1.0000x reference)
//
#include <hip/hip_runtime.h>

typedef __bf16 bf16;
typedef __attribute__((ext_vector_type(4)))  __bf16 bf16x4;
typedef __attribute__((ext_vector_type(8)))  __bf16 bf16x8;
typedef __attribute__((ext_vector_type(4)))  float  f32x4;
typedef __attribute__((ext_vector_type(16))) float  f32x16;

constexpr int B_ = 16, N_ = 256, K_ = 10, C_ = 100;
constexpr float NL2E = -0.7213475204444817f;             // -0.5*log2(e)

__device__ inline bf16x8 cvt8(const float* p) {
    float4 a = *(const float4*)p, b = *(const float4*)(p + 4);
    bf16x8 r = {(bf16)a.x, (bf16)a.y, (bf16)a.z, (bf16)a.w,
                (bf16)b.x, (bf16)b.y, (bf16)b.z, (bf16)b.w};
    return r;
}
__device__ inline bf16x8 cvt4z(const float* p) {          // 4 valid + 4 zeros
    float4 a = *(const float4*)p;
    bf16x8 r = {(bf16)a.x, (bf16)a.y, (bf16)a.z, (bf16)a.w,
                (bf16)0.0f, (bf16)0.0f, (bf16)0.0f, (bf16)0.0f};
    return r;
}

// ---------------------------------------------------------------------------
// Single fused kernel, R18-K2 grid (1280 blocks, (b,k,n32)):
//   ag tile built once (R18 phase-1 verbatim, coalesced, swizzled LDS).
//   Then 8 chunks of 32 m: stage x chunk coalesced -> 7 MFMA xk-GEMM
//   (R17-K1 body, W A-frags in regs) -> xk chunk to 8KB fragment-ready LDS
//   -> 2 phase-2 MFMAs accumulate out. xkT never touches global memory;
//   K1 and its launch are deleted. stage(it+1) overlaps phase-2(it):
//   2 barriers/chunk. LDS 37.5KB -> 4 blocks/CU.
//   Arithmetic bit-identical to R18 (same operands, same order).
// ---------------------------------------------------------------------------
__global__ __launch_bounds__(256, 4) void fused_gauss(
    const float* __restrict__ x, const float* __restrict__ adj,
    const float* __restrict__ pseudo, const float* __restrict__ mu,
    const float* __restrict__ sigma, const float* __restrict__ W,
    const float* __restrict__ bias, float* __restrict__ out)
{
    __shared__ float xs[32 * 101 + 16];            // 12.99KB x-chunk
    __shared__ bf16  xkc[4 * 128 * 8];             // 8KB xk chunk (frag-ready)
    __shared__ __align__(16) char agb[32 * 512];   // 16KB ag tile (swizzled)

    const int bid = blockIdx.x;
    const int xcd = bid & 7, s = bid >> 3;         // s: 0..159
    const int b  = xcd + 8 * (s / 80);
    const int rr = s % 80, kk = rr >> 3, nh = rr & 7;
    const int n32 = nh * 32;
    const int tid = threadIdx.x;
    const int w = tid >> 6, l = tid & 63, l31 = l & 31, h = l >> 5;
    const int c = w * 32 + l31;                    // this wave's c-tile row

    const bf16x8 zf = {(bf16)0.f,(bf16)0.f,(bf16)0.f,(bf16)0.f,
                       (bf16)0.f,(bf16)0.f,(bf16)0.f,(bf16)0.f};

    // ---- W A-frags (R18-K1 verbatim; global L2-hot) ----
    bf16x8 af[7];
    const float* Wrow = W + (size_t)c * C_;
    #pragma unroll
    for (int js = 0; js < 7; ++js) {
        const int jb = js * 16 + h * 8;
        af[js] = zf;
        if (c < C_) {
            if (jb + 8 <= C_)      af[js] = cvt8(Wrow + jb);
            else if (jb < C_)      af[js] = cvt4z(Wrow + jb);   // jb == 96
        }
    }
    float bv[16];
    #pragma unroll
    for (int r = 0; r < 16; ++r) {
        int crow = w * 32 + (r & 3) + 8 * (r >> 2) + 4 * h;
        bv[r] = (crow < C_) ? bias[crow] : 0.0f;
    }

    // ---- gaussian coefs (uniform -> scalar loads) ----
    float Av[4], Bv[4], ga = 0.0f;
    #pragma unroll
    for (int d = 0; d < 4; ++d) {
        float sg = sigma[kk * 4 + d];
        float al = NL2E / (1e-6f + sg * sg);
        float mv = mu[kk * 4 + d];
        Av[d] = al; Bv[d] = -2.0f * al * mv; ga += al * mv * mv;
    }

    // ---- ag tile -> LDS (R18 phase-1 verbatim: coalesced, swizzled) ----
    const float* pbase = pseudo + (size_t)(b * N_ + n32) * N_ * 4;
    const float* abase = adj    + (size_t)(b * N_ + n32) * N_;
    #pragma unroll
    for (int i = 0; i < 8; ++i) {
        const int row = i * 4 + w;                 // wave owns one row/iter
        const float4* pr = (const float4*)(pbase + (size_t)row * N_ * 4);
        const float*  ar = abase + (size_t)row * N_;
        float4 p0 = pr[l];                         // 1KB contiguous per instr
        float4 p1 = pr[l + 64];
        float4 p2 = pr[l + 128];
        float4 p3 = pr[l + 192];
        float a0 = ar[l], a1 = ar[l + 64], a2 = ar[l + 128], a3 = ar[l + 192];

        float s0 = ga + Av[0]*p0.x*p0.x + Bv[0]*p0.x + Av[1]*p0.y*p0.y + Bv[1]*p0.y
                      + Av[2]*p0.z*p0.z + Bv[2]*p0.z + Av[3]*p0.w*p0.w + Bv[3]*p0.w;
        float s1 = ga + Av[0]*p1.x*p1.x + Bv[0]*p1.x + Av[1]*p1.y*p1.y + Bv[1]*p1.y
                      + Av[2]*p1.z*p1.z + Bv[2]*p1.z + Av[3]*p1.w*p1.w + Bv[3]*p1.w;
        float s2 = ga + Av[0]*p2.x*p2.x + Bv[0]*p2.x + Av[1]*p2.y*p2.y + Bv[1]*p2.y
                      + Av[2]*p2.z*p2.z + Bv[2]*p2.z + Av[3]*p2.w*p2.w + Bv[3]*p2.w;
        float s3 = ga + Av[0]*p3.x*p3.x + Bv[0]*p3.x + Av[1]*p3.y*p3.y + Bv[1]*p3.y
                      + Av[2]*p3.z*p3.z + Bv[2]*p3.z + Av[3]*p3.w*p3.w + Bv[3]*p3.w;

        float g0 = __builtin_amdgcn_exp2f(s0) * a0;
        float g1 = __builtin_amdgcn_exp2f(s1) * a1;
        float g2 = __builtin_amdgcn_exp2f(s2) * a2;
        float g3 = __builtin_amdgcn_exp2f(s3) * a3;

        #pragma unroll
        for (int t = 0; t < 4; ++t) {
            const int m  = l + 64 * t;
            const int ch = m >> 3, half = (m >> 2) & 1, pos = m & 3;
            const float gv = (t == 0) ? g0 : (t == 1) ? g1 : (t == 2) ? g2 : g3;
            *(bf16*)(agb + row * 512 + ((ch ^ (row & 7)) * 16) + half * 8 + pos * 2)
                = (bf16)gv;
        }
    }

    f32x16 acc2;                                   // phase-2 accumulator
    #pragma unroll
    for (int i = 0; i < 16; ++i) acc2[i] = 0.0f;

    __syncthreads();                               // ag ready

    // ---- 8 chunks of 32 m: stage -> xk GEMM -> partial aggregation ----
    #pragma unroll 1
    for (int it = 0; it < 8; ++it) {
        // stage x chunk (R17-K1 staging verbatim; overlaps phase-2 of it-1)
        const float* xb = x + ((size_t)(b * N_ + it * 32) * K_ + kk) * C_;
        #pragma unroll 4
        for (int idx = tid; idx < 800; idx += 256) {
            int row = idx / 25, q = idx - row * 25;
            float4 v = *(const float4*)(xb + (size_t)row * (K_ * C_) + q * 4);
            *(float4*)(&xs[row * 101 + q * 4]) = v;
        }
        __syncthreads();                           // xs ready; xkc reads done

        // xk GEMM for this chunk (R17-K1 body; lane l31 = local m)
        f32x16 acc;
        #pragma unroll
        for (int r = 0; r < 16; ++r) acc[r] = bv[r];
        #pragma unroll
        for (int js = 0; js < 7; ++js) {
            const int jb = js * 16 + h * 8;
            bf16x8 b0 = zf;
            if (jb < C_) b0 = cvt8(&xs[l31 * 101 + jb]);  // pad garbage x af==0
            acc = __builtin_amdgcn_mfma_f32_32x32x16_bf16(af[js], b0, acc, 0, 0, 0);
        }
        // store chunk in fragment-ready LDS: [(mloc>>4)*2+((mloc>>3)&1)][c][m&7]
        const int base = (((l31 >> 4) << 1) + ((l31 >> 3) & 1)) * 1024 + (l31 & 7);
        #pragma unroll
        for (int r = 0; r < 16; ++r) {
            const int crow = w * 32 + (r & 3) + 8 * (r >> 2) + 4 * h;
            xkc[base + crow * 8] = (bf16)acc[r];
        }
        __syncthreads();                           // xkc ready

        // phase-2 partial: 2 MFMAs (global ks = it*2 + ks_loc)
        #pragma unroll
        for (int ksl = 0; ksl < 2; ++ksl) {
            const int ksg = it * 2 + ksl;
            bf16x8 a8 = *(const bf16x8*)(agb + l31 * 512
                          + (((ksg * 2 + h) ^ (l31 & 7)) * 16));
            bf16x8 b8 = *(const bf16x8*)(&xkc[(ksl * 2 + h) * 1024 + c * 8]);
            acc2 = __builtin_amdgcn_mfma_f32_32x32x16_bf16(a8, b8, acc2, 0, 0, 0);
        }
        // no barrier here: next stage writes xs only; xkc protected by the
        // barrier after the next stage (phase-2 reads happen before it).
    }

    // ---- epilogue (R18-K2 verbatim) ----
    if (c < C_) {
        float* ob = out + (size_t)(b * K_ + kk) * C_ * N_ + (size_t)c * N_ + n32;
        #pragma unroll
        for (int q = 0; q < 4; ++q) {
            float4 v = {acc2[4*q+0], acc2[4*q+1], acc2[4*q+2], acc2[4*q+3]};
            *(float4*)(ob + 8 * q + 4 * h) = v;
        }
    }
}

extern "C" void kernel_launch(void* const* d_in, const int* in_sizes, int n_in,
                              void* d_out, int out_size, void* d_ws, size_t ws_size,
                              hipStream_t stream)
{
    const float* x      = (const float*)d_in[0];
    const float* adj    = (const float*)d_in[1];
    const float* pseudo = (const float*)d_in[2];
    const float* mu     = (const float*)d_in[3];
    const float* sigma  = (const float*)d_in[4];
    const float* W      = (const float*)d_in[5];
    const float* bias   = (const float*)d_in[6];
    float* out = (float*)d_out;

    hipLaunchKernelGGL(fused_gauss, dim3(B_ * K_ * 8), dim3(256), 0, stream,
                       x, adj, pseudo, mu, sigma, W, bias, out);
}

// Round 22
// 33.548 us; speedup vs baseline: 2.2294x; 2.2294x over previous
//
#include <hip/hip_runtime.h>

typedef __bf16 bf16;
typedef __attribute__((ext_vector_type(4)))  __bf16 bf16x4;
typedef __attribute__((ext_vector_type(8)))  __bf16 bf16x8;
typedef __attribute__((ext_vector_type(4)))  float  f32x4;
typedef __attribute__((ext_vector_type(16))) float  f32x16;

constexpr int B_ = 16, N_ = 256, K_ = 10, C_ = 100, CP_ = 112;
constexpr float NL2E = -0.7213475204444817f;             // -0.5*log2(e)
constexpr int BF_SLICE = 16 * 2 * 128 * 8;               // 32768 bf16 per (b,k)

__device__ inline bf16x8 cvt8(const float* p) {
    float4 a = *(const float4*)p, b = *(const float4*)(p + 4);
    bf16x8 r = {(bf16)a.x, (bf16)a.y, (bf16)a.z, (bf16)a.w,
                (bf16)b.x, (bf16)b.y, (bf16)b.z, (bf16)b.w};
    return r;
}
__device__ inline bf16x8 cvt4z(const float* p) {          // 4 valid + 4 zeros
    float4 a = *(const float4*)p;
    bf16x8 r = {(bf16)a.x, (bf16)a.y, (bf16)a.z, (bf16)a.w,
                (bf16)0.0f, (bf16)0.0f, (bf16)0.0f, (bf16)0.0f};
    return r;
}

// ---------------------------------------------------------------------------
// K1 (R18 verbatim, best): xkT fragment-ready via MFMA 32x32x16, wave=c-tile.
//   Coalesced x staging (unroll 4); scattered fragment-ready global stores
//   (latency-tolerant — R19's LDS-staged variant regressed, R21's LDS-chunk
//   variant bank-conflicted).
// Grid 1280 XCD-swizzled blocks x 256 thr; LDS 12.9KB.
// ---------------------------------------------------------------------------
__global__ __launch_bounds__(256, 4) void xk_gemm(
    const float* __restrict__ x, const float* __restrict__ W,
    const float* __restrict__ bias, bf16* __restrict__ xkT)
{
    __shared__ float xs[32 * 101 + 16];            // [m32][100+pad]

    const int bid = blockIdx.x;
    const int xcd = bid & 7, s = bid >> 3;         // s: 0..159
    const int b  = xcd + 8 * (s / 80);
    const int rr = s % 80, kk = rr >> 3, mq = rr & 7;
    const int tid = threadIdx.x;
    const int w = tid >> 6, l = tid & 63, l31 = l & 31, h = l >> 5;
    const int c = w * 32 + l31;                    // A row this lane loads

    // ---- coalesced x staging: 32 rows x 100 floats (row stride 1000) ----
    const float* xb = x + ((size_t)(b * N_ + mq * 32) * K_ + kk) * C_;
    #pragma unroll 4
    for (int idx = tid; idx < 800; idx += 256) {   // 800 float4s
        int row = idx / 25, q = idx - row * 25;
        float4 v = *(const float4*)(xb + (size_t)row * (K_ * C_) + q * 4);
        *(float4*)(&xs[row * 101 + q * 4]) = v;
    }

    const bf16x8 zf = {(bf16)0.f,(bf16)0.f,(bf16)0.f,(bf16)0.f,
                       (bf16)0.f,(bf16)0.f,(bf16)0.f,(bf16)0.f};

    // A-frags from global W (40KB, L1/L2-hot)
    bf16x8 af[7];
    const float* Wrow = W + (size_t)c * C_;
    #pragma unroll
    for (int js = 0; js < 7; ++js) {
        const int jb = js * 16 + h * 8;
        af[js] = zf;
        if (c < C_) {
            if (jb + 8 <= C_)      af[js] = cvt8(Wrow + jb);
            else if (jb < C_)      af[js] = cvt4z(Wrow + jb);   // jb == 96
        }
    }

    f32x16 acc;
    #pragma unroll
    for (int r = 0; r < 16; ++r) {
        int crow = w * 32 + (r & 3) + 8 * (r >> 2) + 4 * h;
        acc[r] = (crow < C_) ? bias[crow] : 0.0f;
    }

    __syncthreads();

    // ---- B-frags from LDS + MFMA ----
    #pragma unroll
    for (int js = 0; js < 7; ++js) {
        const int jb = js * 16 + h * 8;            // up to 104; padded array
        bf16x8 b0 = zf;
        if (jb < C_) b0 = cvt8(&xs[l31 * 101 + jb]);  // pad garbage x af==0
        acc = __builtin_amdgcn_mfma_f32_32x32x16_bf16(af[js], b0, acc, 0, 0, 0);
    }

    // ---- store in fragment-ready layout: Bf[ks][h][c][i], i=m&7 ----
    bf16* op = xkT + (size_t)(b * K_ + kk) * BF_SLICE;
    const int mg = mq * 32 + l31;
    const int base = (((mg >> 4) << 1) + ((mg >> 3) & 1)) * 1024 + (mg & 7);
    #pragma unroll
    for (int r = 0; r < 16; ++r) {
        const int crow = w * 32 + (r & 3) + 8 * (r >> 2) + 4 * h;
        op[base + crow * 8] = (bf16)acc[r];
    }
}

// ---------------------------------------------------------------------------
// K2 (R18 verbatim, best): out[b,k][c][n] = sum_m ag[n,m]*xk[m,c], ag fused.
//   Phase 1: coalesced pseudo/adj loads (wave = row, lane j -> m in
//   {j, j+64, j+128, j+192}; 1KB contiguous per instr), full unroll,
//   swizzled scalar bf16 LDS stores. Phase 2: A via swizzled ds_read_b128,
//   B line-contiguous from fragment-ready xkT. One barrier.
// Grid 1280 blocks x 256 thr, 16KB LDS.
// ---------------------------------------------------------------------------
__global__ __launch_bounds__(256, 4) void gauss_agg(
    const float* __restrict__ adj, const float* __restrict__ pseudo,
    const float* __restrict__ mu, const float* __restrict__ sigma,
    const bf16* __restrict__ xkT, float* __restrict__ out)
{
    __shared__ __align__(16) char lds[32 * 512];   // ag tile, 16B-chunk swizzle

    const int bid = blockIdx.x;
    const int xcd = bid & 7, s = bid >> 3;         // s: 0..159
    const int b  = xcd + 8 * (s / 80);
    const int rr = s % 80, kk = rr >> 3, nh = rr & 7;
    const int n32 = nh * 32;
    const int tid = threadIdx.x;
    const int w = tid >> 6, l = tid & 63, l31 = l & 31, h = l >> 5;

    // per-thread gaussian coefs (kk uniform -> scalar loads)
    float Av[4], Bv[4], ga = 0.0f;
    #pragma unroll
    for (int d = 0; d < 4; ++d) {
        float sg = sigma[kk * 4 + d];
        float al = NL2E / (1e-6f + sg * sg);
        float mv = mu[kk * 4 + d];
        Av[d] = al; Bv[d] = -2.0f * al * mv; ga += al * mv * mv;
    }

    // ---- phase 1: ag tile -> LDS (coalesced loads, full unroll) ----
    const float* pbase = pseudo + (size_t)(b * N_ + n32) * N_ * 4;
    const float* abase = adj    + (size_t)(b * N_ + n32) * N_;
    #pragma unroll
    for (int i = 0; i < 8; ++i) {
        const int row = i * 4 + w;                 // wave owns one row/iter
        const float4* pr = (const float4*)(pbase + (size_t)row * N_ * 4);
        const float*  ar = abase + (size_t)row * N_;
        float4 p0 = pr[l];                         // 1KB contiguous per instr
        float4 p1 = pr[l + 64];
        float4 p2 = pr[l + 128];
        float4 p3 = pr[l + 192];
        float a0 = ar[l], a1 = ar[l + 64], a2 = ar[l + 128], a3 = ar[l + 192];

        float s0 = ga + Av[0]*p0.x*p0.x + Bv[0]*p0.x + Av[1]*p0.y*p0.y + Bv[1]*p0.y
                      + Av[2]*p0.z*p0.z + Bv[2]*p0.z + Av[3]*p0.w*p0.w + Bv[3]*p0.w;
        float s1 = ga + Av[0]*p1.x*p1.x + Bv[0]*p1.x + Av[1]*p1.y*p1.y + Bv[1]*p1.y
                      + Av[2]*p1.z*p1.z + Bv[2]*p1.z + Av[3]*p1.w*p1.w + Bv[3]*p1.w;
        float s2 = ga + Av[0]*p2.x*p2.x + Bv[0]*p2.x + Av[1]*p2.y*p2.y + Bv[1]*p2.y
                      + Av[2]*p2.z*p2.z + Bv[2]*p2.z + Av[3]*p2.w*p2.w + Bv[3]*p2.w;
        float s3 = ga + Av[0]*p3.x*p3.x + Bv[0]*p3.x + Av[1]*p3.y*p3.y + Bv[1]*p3.y
                      + Av[2]*p3.z*p3.z + Bv[2]*p3.z + Av[3]*p3.w*p3.w + Bv[3]*p3.w;

        float g0 = __builtin_amdgcn_exp2f(s0) * a0;
        float g1 = __builtin_amdgcn_exp2f(s1) * a1;
        float g2 = __builtin_amdgcn_exp2f(s2) * a2;
        float g3 = __builtin_amdgcn_exp2f(s3) * a3;

        #pragma unroll
        for (int t = 0; t < 4; ++t) {
            const int m  = l + 64 * t;
            const int ch = m >> 3, half = (m >> 2) & 1, pos = m & 3;
            const float gv = (t == 0) ? g0 : (t == 1) ? g1 : (t == 2) ? g2 : g3;
            *(bf16*)(lds + row * 512 + ((ch ^ (row & 7)) * 16) + half * 8 + pos * 2)
                = (bf16)gv;
        }
    }
    __syncthreads();

    // ---- phase 2: MFMA, B-frags line-contiguous ----
    const bf16* bsl = xkT + (size_t)(b * K_ + kk) * BF_SLICE
                          + (size_t)(w * 32 + l31) * 8;
    f32x16 acc;
    #pragma unroll
    for (int i = 0; i < 16; ++i) acc[i] = 0.0f;

    #pragma unroll
    for (int ks = 0; ks < 16; ++ks) {
        bf16x8 af = *(const bf16x8*)(lds + l31 * 512 + (((ks * 2 + h) ^ (l31 & 7)) * 16));
        bf16x8 bf = *(const bf16x8*)(bsl + (size_t)(ks * 2 + h) * 1024);
        acc = __builtin_amdgcn_mfma_f32_32x32x16_bf16(af, bf, acc, 0, 0, 0);
    }

    const int c = w * 32 + l31;
    if (c < C_) {
        float* ob = out + (size_t)(b * K_ + kk) * C_ * N_ + (size_t)c * N_ + n32;
        #pragma unroll
        for (int q = 0; q < 4; ++q) {
            float4 v = {acc[4*q+0], acc[4*q+1], acc[4*q+2], acc[4*q+3]};
            *(float4*)(ob + 8 * q + 4 * h) = v;
        }
    }
}

extern "C" void kernel_launch(void* const* d_in, const int* in_sizes, int n_in,
                              void* d_out, int out_size, void* d_ws, size_t ws_size,
                              hipStream_t stream)
{
    const float* x      = (const float*)d_in[0];
    const float* adj    = (const float*)d_in[1];
    const float* pseudo = (const float*)d_in[2];
    const float* mu     = (const float*)d_in[3];
    const float* sigma  = (const float*)d_in[4];
    const float* W      = (const float*)d_in[5];
    const float* bias   = (const float*)d_in[6];
    float* out = (float*)d_out;
    bf16* xkT  = (bf16*)d_ws;                      // 10.5 MB fragment-ready

    hipLaunchKernelGGL(xk_gemm, dim3(1280), dim3(256), 0, stream, x, W, bias, xkT);
    hipLaunchKernelGGL(gauss_agg, dim3(1280), dim3(256), 0, stream,
                       adj, pseudo, mu, sigma, xkT, out);
}